// Round 11
// baseline (244.174 us; speedup 1.0000x reference)
//
#include <hip/hip_runtime.h>
#include <hip/hip_bf16.h>
#include <hip/hip_fp16.h>
#include <hip/hip_fp8.h>

// DeformableAttention on MI355X.
// prep(weights^T bf16) -> gemm_bf16(q) -> fused conv+LN+GELU+pos+sample ->
// gemm_bf16(kv) -> build_rpe8_zero(rpeq table + zero Oaccum/laccum; AFTER
// kv-GEMM because Oaccum aliases the then-dead xsb) -> fused flash-attn
// v10c (round-1 proven body; j-split across block pairs, grid 2048; 36-row
// rpe window coalesced-copied -> 23.3 KB LDS -> ~7 blocks/CU; partials via
// 2 deterministic f32 atomicAdds) -> gemm_bf16(out,+bias; normalize via lrow)
// v10c fixes v10b's layout: xsb is 1,048,576 f32 (8192*256 bf16), not
// 524,288 -- v10b placed Wkvt/Woutt/Wqt/rpeq inside xsb and conv clobbered
// them.  New layout: small tables before xsb; Oaccum aliases xsb (dead
// after kv-GEMM); zeroing deferred to after step 4.  Total 26.2 MB.

#define EPS_ 1e-5f
#define ASCALE 0.17677669529663687f      // 1/sqrt(32)
#define LOG2E  1.4426950408889634f

typedef __attribute__((ext_vector_type(8))) short bf16x8;
typedef __attribute__((ext_vector_type(4))) float f32x4;

__device__ __forceinline__ short f2bf(float f) {
  union { float f; unsigned u; } v; v.f = f;
  unsigned r = (v.u + 0x7fffu + ((v.u >> 16) & 1u)) >> 16;  // RNE
  return (short)r;
}
__device__ __forceinline__ unsigned pk2bf(float a, float b) {
  union { __hip_bfloat162 h; unsigned u; } v;
  v.h = __float22bfloat162_rn(make_float2(a, b));
  return v.u;
}
__device__ __forceinline__ float exp2_fast(float x) {
  return __builtin_amdgcn_exp2f(x);
}

// fp8 e4m3 quad pack/unpack: HW v_cvt_pk_* on gfx950, sw fallback otherwise.
__device__ __forceinline__ unsigned pack_fp8_quad(float v00, float v10,
                                                  float v01, float v11) {
#if __has_builtin(__builtin_amdgcn_cvt_pk_fp8_f32)
  int r = 0;
  r = __builtin_amdgcn_cvt_pk_fp8_f32(v00, v10, r, false);  // bytes 0,1
  r = __builtin_amdgcn_cvt_pk_fp8_f32(v01, v11, r, true);   // bytes 2,3
  return (unsigned)r;
#else
  __hip_fp8x2_e4m3 elo(make_float2(v00, v10));
  __hip_fp8x2_e4m3 ehi(make_float2(v01, v11));
  return (unsigned)(unsigned short)elo.__x |
         ((unsigned)(unsigned short)ehi.__x << 16);
#endif
}
__device__ __forceinline__ void unpack_fp8_quad(unsigned u, float& g00,
                                                float& g10, float& g01,
                                                float& g11) {
#if __has_builtin(__builtin_amdgcn_cvt_pk_f32_fp8)
  auto ga = __builtin_amdgcn_cvt_pk_f32_fp8((int)u, false);  // (v00, v10)
  auto gb = __builtin_amdgcn_cvt_pk_f32_fp8((int)u, true);   // (v01, v11)
  g00 = ga[0]; g10 = ga[1]; g01 = gb[0]; g11 = gb[1];
#else
  __hip_fp8x2_e4m3 plo, phi;
  plo.__x = (__hip_fp8x2_storage_t)(unsigned short)(u & 0xffffu);
  phi.__x = (__hip_fp8x2_storage_t)(unsigned short)(u >> 16);
  float2 fa = (float2)plo, fb = (float2)phi;
  g00 = fa.x; g10 = fa.y; g01 = fb.x; g11 = fb.y;
#endif
}

// ---------------------------------------------------------------------------
// Weight prep: Wkvt[n][k]=bf16(Wkv[k][n]); Woutt, Wqt likewise.
// ---------------------------------------------------------------------------
__global__ __launch_bounds__(256) void prep_weights(
    const float* __restrict__ Wkv, const float* __restrict__ Wout,
    const float* __restrict__ Wq, short* __restrict__ Wkvt,
    short* __restrict__ Woutt, short* __restrict__ Wqt)
{
  int bid = blockIdx.x, k = threadIdx.x;
  if (bid < 512) Wkvt[bid * 256 + k] = f2bf(Wkv[k * 512 + bid]);
  else if (bid < 768) { int n = bid - 512; Woutt[n * 256 + k] = f2bf(Wout[k * 256 + n]); }
  else { int n = bid - 768; Wqt[n * 256 + k] = f2bf(Wq[k * 256 + n]); }
}

// ---------------------------------------------------------------------------
// Combined (launched AFTER the kv-GEMM, since Oaccum aliases dead xsb):
// bids [0,128):        build fp8 rpe quad table rpeq (8 x 64 x 64 u32)
// bids [128,2176):     zero Oaccum  (2,097,152 f32, float4 stores)
// bids [2176,2240):    zero laccum  (65,536 f32, float4 stores)
// ---------------------------------------------------------------------------
__global__ __launch_bounds__(256) void build_rpe8_zero(
    const float* __restrict__ rpe, unsigned* __restrict__ rpeq,
    float* __restrict__ Oaccum, float* __restrict__ laccum)
{
  int bid = blockIdx.x, t = threadIdx.x;
  if (bid >= 2176) {
    ((float4*)laccum)[(size_t)(bid - 2176) * 256 + t] = make_float4(0.f, 0.f, 0.f, 0.f);
    return;
  }
  if (bid >= 128) {
    ((float4*)Oaccum)[(size_t)(bid - 128) * 256 + t] = make_float4(0.f, 0.f, 0.f, 0.f);
    return;
  }
  int i = bid * 256 + t;   // 0..32767
  int h = i >> 12, idx = i & 4095;
  int ty = idx >> 6, tx = idx & 63;
  const float* rp = rpe + h * 3969;
  float v00 = 0.f, v10 = 0.f, v01 = 0.f, v11 = 0.f;
  if (tx <= 62) {
    if (ty <= 62) v00 = rp[ty * 63 + tx] * LOG2E;
    if (ty <= 61) v10 = rp[(ty + 1) * 63 + tx] * LOG2E;
  }
  if (tx <= 61) {
    if (ty <= 62) v01 = rp[ty * 63 + tx + 1] * LOG2E;
    if (ty <= 61) v11 = rp[(ty + 1) * 63 + tx + 1] * LOG2E;
  }
  rpeq[i] = pack_fp8_quad(v00, v10, v01, v11);
}

// ---------------------------------------------------------------------------
// bf16 MFMA GEMM: C[M,N] = A[M,256] @ Bt[N,256]^T (+bias), with prefetch.
// If lrow != null (with Af): A[m][k] = Af[m][k] / lrow[m*8 + k/32].
// ---------------------------------------------------------------------------
__global__ __launch_bounds__(256) void gemm_bf16(
    const short* __restrict__ Ab, const float* __restrict__ Af,
    const short* __restrict__ Bt,
    float* __restrict__ Cf, short* __restrict__ Cb,
    const float* __restrict__ bias, int N, const float* __restrict__ lrow)
{
  __shared__ __align__(16) short As[64 * 40];
  __shared__ __align__(16) short Bs[64 * 40];
  const int t = threadIdx.x;
  const int n0 = blockIdx.x << 6, m0 = blockIdx.y << 6;
  const int wv = t >> 6, l16 = t & 15, quad = (t & 63) >> 4;
  const int row = t >> 2, koff = (t & 3) << 3;

  auto loadA = [&](int k0) -> bf16x8 {
    if (Af) {
      const float* src = &Af[(size_t)(m0 + row) * 256 + k0 + koff];
      float4 f0 = *(const float4*)src;
      float4 f1 = *(const float4*)(src + 4);
      float s = 1.f;
      if (lrow) s = 1.f / lrow[(size_t)(m0 + row) * 8 + ((k0 + koff) >> 5)];
      union { unsigned u[4]; bf16x8 v; } c;
      c.u[0] = pk2bf(f0.x * s, f0.y * s); c.u[1] = pk2bf(f0.z * s, f0.w * s);
      c.u[2] = pk2bf(f1.x * s, f1.y * s); c.u[3] = pk2bf(f1.z * s, f1.w * s);
      return c.v;
    }
    return *(const bf16x8*)&Ab[(size_t)(m0 + row) * 256 + k0 + koff];
  };

  f32x4 acc[4] = {};
  bf16x8 av = loadA(0);
  bf16x8 bv = *(const bf16x8*)&Bt[(size_t)(n0 + row) * 256 + koff];
  for (int k0 = 0; k0 < 256; k0 += 32) {
    __syncthreads();  // prior-iter frag reads done before overwrite
    *(bf16x8*)&As[row * 40 + koff] = av;
    *(bf16x8*)&Bs[row * 40 + koff] = bv;
    __syncthreads();
    if (k0 + 32 < 256) {  // prefetch next chunk before MFMA section
      av = loadA(k0 + 32);
      bv = *(const bf16x8*)&Bt[(size_t)(n0 + row) * 256 + k0 + 32 + koff];
    }
    bf16x8 a = *(const bf16x8*)&As[((wv << 4) + l16) * 40 + (quad << 3)];
#pragma unroll
    for (int jt = 0; jt < 4; jt++) {
      bf16x8 bb = *(const bf16x8*)&Bs[((jt << 4) + l16) * 40 + (quad << 3)];
      acc[jt] = __builtin_amdgcn_mfma_f32_16x16x32_bf16(a, bb, acc[jt], 0, 0, 0);
    }
  }
#pragma unroll
  for (int jt = 0; jt < 4; jt++) {
#pragma unroll
    for (int r = 0; r < 4; r++) {
      int mrow = m0 + (wv << 4) + (quad << 2) + r;
      int ncol = n0 + (jt << 4) + l16;
      float v = acc[jt][r];
      if (bias) v += bias[ncol];
      if (Cf) Cf[(size_t)mrow * N + ncol] = v;
      else    Cb[(size_t)mrow * N + ncol] = f2bf(v);
    }
  }
}

// ---------------------------------------------------------------------------
// Fused: conv5x5 depthwise + LN(128) + GELU + @Woff + tanh -> pos, then
// grid_sample of this pixel's group channels -> xs (bf16). Wave per (b,g,pix).
// ---------------------------------------------------------------------------
__global__ __launch_bounds__(256) void conv_pos_sample_kernel(
    const float* __restrict__ q, const float* __restrict__ conv_w,
    const float* __restrict__ conv_b, const float* __restrict__ ln_g,
    const float* __restrict__ ln_b, const float* __restrict__ Woff,
    float* __restrict__ pos, short* __restrict__ xsb)
{
  const int p = (blockIdx.x << 2) + (threadIdx.x >> 6);
  const int lane = threadIdx.x & 63;
  const int bg = p >> 10, pix = p & 1023;
  const int hh = pix >> 5, ww = pix & 31;
  const int b = bg >> 1, g = bg & 1;
  const int c0 = lane << 1;

  float2 cb = *(const float2*)&conv_b[c0];
  float a0 = cb.x, a1 = cb.y;
  const float* w0 = conv_w + c0 * 25;
  const float* w1 = w0 + 25;
#pragma unroll
  for (int dy = 0; dy < 5; dy++) {
    int y = hh + dy - 2;
    if ((unsigned)y < 32u) {
#pragma unroll
      for (int dx = 0; dx < 5; dx++) {
        int x = ww + dx - 2;
        if ((unsigned)x < 32u) {
          float2 qv = *(const float2*)&q[(size_t)((b << 10) + (y << 5) + x) * 256 + (g << 7) + c0];
          a0 = fmaf(qv.x, w0[dy * 5 + dx], a0);
          a1 = fmaf(qv.y, w1[dy * 5 + dx], a1);
        }
      }
    }
  }
  float s1 = a0 + a1, s2 = a0 * a0 + a1 * a1;
#pragma unroll
  for (int o = 32; o; o >>= 1) { s1 += __shfl_xor(s1, o); s2 += __shfl_xor(s2, o); }
  float mu = s1 * (1.f / 128.f);
  float inv = rsqrtf(fmaf(-mu, mu, s2 * (1.f / 128.f)) + EPS_);
  float2 lg = *(const float2*)&ln_g[c0];
  float2 lb = *(const float2*)&ln_b[c0];
  float v0 = (a0 - mu) * inv * lg.x + lb.x;
  float v1 = (a1 - mu) * inv * lg.y + lb.y;
  float ge0 = 0.5f * v0 * (1.f + erff(v0 * 0.70710678118654752f));
  float ge1 = 0.5f * v1 * (1.f + erff(v1 * 0.70710678118654752f));
  float2 W0 = *(const float2*)&Woff[c0 * 2];
  float2 W1 = *(const float2*)&Woff[c0 * 2 + 2];
  float o0 = ge0 * W0.x + ge1 * W1.x;
  float o1 = ge0 * W0.y + ge1 * W1.y;
#pragma unroll
  for (int o = 32; o; o >>= 1) { o0 += __shfl_xor(o0, o); o1 += __shfl_xor(o1, o); }
  float py = tanhf(o0) * 0.0625f + ((hh + 0.5f) * 0.0625f - 1.f);
  float px = tanhf(o1) * 0.0625f + ((ww + 0.5f) * 0.0625f - 1.f);
  if (lane == 0)
    ((float2*)pos)[(bg << 10) + pix] = make_float2(py, px);

  float x = (px + 1.f) * 15.5f;
  float y = (py + 1.f) * 15.5f;
  float x0f = floorf(x), y0f = floorf(y);
  int ix0 = (int)x0f, iy0 = (int)y0f;
  float fx = x - x0f, fy = y - y0f;
  float ac0 = 0.f, ac1 = 0.f;
#pragma unroll
  for (int dy = 0; dy < 2; dy++) {
#pragma unroll
    for (int dx = 0; dx < 2; dx++) {
      int yi = iy0 + dy, xi = ix0 + dx;
      float w = (dy ? fy : 1.f - fy) * (dx ? fx : 1.f - fx);
      if ((unsigned)yi < 32u && (unsigned)xi < 32u) {
        float2 qv = *(const float2*)&q[(size_t)((b << 10) + (yi << 5) + xi) * 256 + (g << 7) + c0];
        ac0 = fmaf(w, qv.x, ac0);
        ac1 = fmaf(w, qv.y, ac1);
      }
    }
  }
  *(unsigned*)&xsb[(size_t)((b << 10) + pix) * 256 + (g << 7) + c0] = pk2bf(ac0, ac1);
}

// ---------------------------------------------------------------------------
// Fused attention v10c = round-1 proven body + block-pair j-split.
// Grid dim3(32, 8, 8): it = bx>>1, half = bx&1 -> kt in [half*8, half*8+8)
// over the same 64 rows.  rpe8 staged from the prebuilt global table by a
// coalesced 36-row-window copy.  LDS 23.3 KB -> ~7 blocks/CU.
// Partials via f32 atomicAdd (2 adds/location, deterministic).
// ---------------------------------------------------------------------------
__global__ __launch_bounds__(256, 4) void attn_kernel(
    const float* __restrict__ q, const short* __restrict__ kvb,
    const float* __restrict__ pos, const unsigned* __restrict__ rpeq,
    float* __restrict__ Oaccum, float* __restrict__ laccum)
{
  const int it = blockIdx.x >> 1, half = blockIdx.x & 1;
  const int h = blockIdx.y, b = blockIdx.z;
  const int g = h >> 2, t = threadIdx.x;
  const int wv = t >> 6, l16 = t & 15, quad = (t & 63) >> 4;

  __shared__ __align__(16) short PL[64 * 72];       // P (wave-local rows)
  __shared__ __align__(16) short Vt[32 * 68];       // V^T [d][j]
  __shared__ float2 posT[64];                       // (-15.5*py, -15.5*px)
  __shared__ __align__(16) unsigned rpe8[36 * 64];  // fp8 quad window

  // ---- block-uniform y-window (bounds v7-validated on HW)
  const float aycb = 15.5f * ((2 * it + 0.5f) * 0.0625f - 1.f) + 31.f;
  int ylo = (int)floorf(aycb) - 16;
  ylo = ylo < 0 ? 0 : (ylo > 28 ? 28 : ylo);

  // ---- stage rpe window: coalesced copy from prebuilt global table
  {
    const unsigned* src = rpeq + (h << 12) + (ylo << 6);
    for (int i = t; i < 36 * 64; i += 256) rpe8[i] = src[i];
  }

  // ---- Q A-frag from global (once), scaled by ASCALE*LOG2E
  const int row0 = (it << 6) + (wv << 4);
  bf16x8 aq;
  {
    const float* src = q + (size_t)((b << 10) + row0 + l16) * 256 + (h << 5) + (quad << 3);
    float4 f0 = *(const float4*)src;
    float4 f1 = *(const float4*)(src + 4);
    const float sc = ASCALE * LOG2E;
    union { unsigned u[4]; bf16x8 v; } c;
    c.u[0] = pk2bf(f0.x * sc, f0.y * sc); c.u[1] = pk2bf(f0.z * sc, f0.w * sc);
    c.u[2] = pk2bf(f1.x * sc, f1.y * sc); c.u[3] = pk2bf(f1.z * sc, f1.w * sc);
    aq = c.v;
  }

  // sampling coords (origin +31): wave's 16 rows share one raster row
  const float ayc = 15.5f * (((row0 >> 5) + 0.5f) * 0.0625f - 1.f) + 31.f;
  float ax[4];
#pragma unroll
  for (int r = 0; r < 4; r++) {
    int ix = (row0 & 31) + (quad << 2) + r;
    ax[r] = 15.5f * ((ix + 0.5f) * 0.0625f - 1.f) + 31.f;
  }

  bf16x8 vones;
#pragma unroll
  for (int i = 0; i < 8; i++) vones[i] = (short)0x3F80;  // bf16 1.0

  // ---- strength-reduced pointer bases, offset to this block's kt range
  const int kt0 = half << 3;
  const int vj = t & 63, vc = t >> 6;
  const short* vsrc = kvb + (size_t)((b << 10) + (kt0 << 6) + vj) * 512 + 256 + (h << 5) + (vc << 3);
  const short* ksrc = kvb + (size_t)((b << 10) + (kt0 << 6) + l16) * 512 + (h << 5) + (quad << 3);
  const float2* psrc = (const float2*)pos + (((b << 1) + g) << 10) + (kt0 << 6) + t;

  f32x4 Oacc[2] = {};
  f32x4 lacc = {};

  for (int kt = 0; kt < 8; kt++) {
    __syncthreads();  // [b1] prior PV reads done (covers rpe8 copy at kt=0)
    // ---- stage V^T: thread (j = t&63, c = t>>6) -> d = c*8..c*8+7
    {
      bf16x8 vv = *(const bf16x8*)vsrc;
#pragma unroll
      for (int k2 = 0; k2 < 8; k2++) Vt[((vc << 3) + k2) * 68 + vj] = vv[k2];
    }
    if (t < 64) {
      float2 pp = *psrc;
      posT[t] = make_float2(-15.5f * pp.x, -15.5f * pp.y);
    }
    __syncthreads();  // [b2]

    // ---- QK^T first: 4 K B-frags from global (L1) + 4 MFMA, before bias
    f32x4 S[4];
#pragma unroll
    for (int jt = 0; jt < 4; jt++) {
      bf16x8 bk = *(const bf16x8*)(ksrc + (size_t)jt * 8192);
      f32x4 z = {};
      S[jt] = __builtin_amdgcn_mfma_f32_16x16x32_bf16(aq, bk, z, 0, 0, 0);
    }

    // ---- y-chains for the 4 j's (posT broadcast reads), hoisted
    float fyv[4];
    int ybv[4];
    float wyv[4];
#pragma unroll
    for (int jt = 0; jt < 4; jt++) {
      float2 bv = posT[(jt << 4) + l16];
      float ys = ayc + bv.x;
      float y0f = floorf(ys);
      fyv[jt] = ys - y0f;
      ybv[jt] = ((int)y0f - ylo) << 6;
      wyv[jt] = bv.y;
    }

    // ---- bias sample + p = exp2(S+bias), per jt
    unsigned pu[4][2];
#pragma unroll
    for (int jt = 0; jt < 4; jt++) {
      float fy = fyv[jt];
      int ybase = ybv[jt];
      float pv[4];
#pragma unroll
      for (int r = 0; r < 4; r++) {
        float sx = ax[r] + wyv[jt];
        float x0f = floorf(sx);
        float fx = sx - x0f;
        unsigned u = rpe8[ybase + (int)x0f];
        float g00, g10, g01, g11;
        unpack_fp8_quad(u, g00, g10, g01, g11);
        float h0 = fmaf(fx, g01 - g00, g00);
        float h1 = fmaf(fx, g11 - g10, g10);
        float bias = fmaf(fy, h1 - h0, h0);
        pv[r] = exp2_fast(S[jt][r] + bias);
      }
      pu[jt][0] = pk2bf(pv[0], pv[1]);
      pu[jt][1] = pk2bf(pv[2], pv[3]);
    }

    // ---- wave-local P write -> A-frag read -> PV + l (no barrier)
#pragma unroll
    for (int jt = 0; jt < 4; jt++) {
      int cb = (jt << 4) + l16;
      int rb = ((wv << 4) + (quad << 2)) * 72 + cb;
      PL[rb]       = (short)(pu[jt][0] & 0xffff);
      PL[rb + 72]  = (short)(pu[jt][0] >> 16);
      PL[rb + 144] = (short)(pu[jt][1] & 0xffff);
      PL[rb + 216] = (short)(pu[jt][1] >> 16);
    }
    bf16x8 pa0 = *(const bf16x8*)&PL[((wv << 4) + l16) * 72 + (quad << 3)];
    bf16x8 pa1 = *(const bf16x8*)&PL[((wv << 4) + l16) * 72 + 32 + (quad << 3)];
#pragma unroll
    for (int dt = 0; dt < 2; dt++) {
      bf16x8 vb0 = *(const bf16x8*)&Vt[((dt << 4) + l16) * 68 + (quad << 3)];
      bf16x8 vb1 = *(const bf16x8*)&Vt[((dt << 4) + l16) * 68 + 32 + (quad << 3)];
      Oacc[dt] = __builtin_amdgcn_mfma_f32_16x16x32_bf16(pa0, vb0, Oacc[dt], 0, 0, 0);
      Oacc[dt] = __builtin_amdgcn_mfma_f32_16x16x32_bf16(pa1, vb1, Oacc[dt], 0, 0, 0);
    }
    lacc = __builtin_amdgcn_mfma_f32_16x16x32_bf16(pa0, vones, lacc, 0, 0, 0);
    lacc = __builtin_amdgcn_mfma_f32_16x16x32_bf16(pa1, vones, lacc, 0, 0, 0);

    // advance strength-reduced pointers (64 rows * 512 shorts; 64 float2)
    vsrc += 32768; ksrc += 32768; psrc += 64;
  }

  // ---- partial accumulation: exactly 2 atomic adds per location (det.)
#pragma unroll
  for (int r = 0; r < 4; r++) {
    int row = row0 + (quad << 2) + r;
    size_t mb = (size_t)((b << 10) + row);
#pragma unroll
    for (int dt = 0; dt < 2; dt++)
      atomicAdd(&Oaccum[mb * 256 + (h << 5) + (dt << 4) + l16], Oacc[dt][r]);
    if (l16 == 0)
      atomicAdd(&laccum[mb * 8 + h], lacc[r]);
  }
}

// ---------------------------------------------------------------------------
extern "C" void kernel_launch(void* const* d_in, const int* in_sizes, int n_in,
                              void* d_out, int out_size, void* d_ws, size_t ws_size,
                              hipStream_t stream) {
  (void)in_sizes; (void)n_in; (void)out_size; (void)ws_size;
  const float* x      = (const float*)d_in[0];
  const float* Wq     = (const float*)d_in[1];
  const float* Wkv    = (const float*)d_in[2];
  const float* conv_w = (const float*)d_in[3];
  const float* conv_b = (const float*)d_in[4];
  const float* ln_g   = (const float*)d_in[5];
  const float* ln_b   = (const float*)d_in[6];
  const float* Woff   = (const float*)d_in[7];
  const float* rpe    = (const float*)d_in[8];
  const float* Wout   = (const float*)d_in[9];
  const float* bout   = (const float*)d_in[10];
  float* out = (float*)d_out;

  // f32-unit offsets; xsb is 8192*256 bf16 = 1,048,576 f32 (v10b had 524,288
  // -- THE bug).  Oaccum ALIASES xsb's region (xsb dead after kv-GEMM;
  // zeroing deferred to build_rpe8_zero, after step 4).
  float* ws       = (float*)d_ws;
  float* q        = ws;                        // [0        .. 2097152)
  float* pos      = ws + 2097152;              // [2097152  .. 2129920)
  short* kvb      = (short*)(ws + 2129920);    // 2,097,152 f32 [2129920 .. 4227072)
  short* Wkvt     = (short*)(ws + 4227072);    //    65,536 f32 [4227072 .. 4292608)
  short* Woutt    = (short*)(ws + 4292608);    //    32,768 f32 [4292608 .. 4325376)
  short* Wqt      = (short*)(ws + 4325376);    //    32,768 f32 [4325376 .. 4358144)
  unsigned* rpeq  = (unsigned*)(ws + 4358144); //    32,768 f32 [4358144 .. 4390912)
  float* laccum   = ws + 4390912;              //    65,536 f32 [4390912 .. 4456448)
  short* xsb      = (short*)(ws + 4456448);    // 1,048,576 f32 [4456448 .. 5505024)  (dead after step 4)
  float* Oaccum   = ws + 4456448;              // 2,097,152 f32 [4456448 .. 6553600)  (aliases xsb)
  // total 6,553,600 f32 = 26.2 MB (v7 proved >= 30.3 MB available)

  // 0. weight transposes
  prep_weights<<<1024, 256, 0, stream>>>(Wkv, Wout, Wq, Wkvt, Woutt, Wqt);
  // 1. q = x @ Wq (bf16 MFMA, f32 A staged+converted, f32 out)
  gemm_bf16<<<dim3(4, 128), 256, 0, stream>>>(nullptr, x, Wqt, q, nullptr, nullptr, 256, nullptr);
  // 2+3. conv + LN + GELU + Woff + tanh -> pos, fused grid_sample -> xs
  conv_pos_sample_kernel<<<4096, 256, 0, stream>>>(q, conv_w, conv_b, ln_g, ln_b,
                                                   Woff, pos, xsb);
  // 4. kv = xs @ Wkv (bf16 MFMA, bf16 out, interleaved K|V rows)
  gemm_bf16<<<dim3(8, 128), 256, 0, stream>>>(xsb, nullptr, Wkvt, nullptr, kvb, nullptr, 512, nullptr);
  // 4b. rpeq table + zero Oaccum/laccum (must be after step 4: alias)
  build_rpe8_zero<<<2240, 256, 0, stream>>>(rpe, rpeq, Oaccum, laccum);
  // 5. fused attention v10c (j-split pairs, ~7 blocks/CU) -> Oaccum/laccum
  attn_kernel<<<dim3(32, 8, 8), 256, 0, stream>>>(q, kvb, pos, rpeq, Oaccum, laccum);
  // 6. out = (Oaccum/laccum) @ Wout + bout (normalize fused into A-load)
  gemm_bf16<<<dim3(4, 128), 256, 0, stream>>>(nullptr, Oaccum, Woutt, out, nullptr, bout, 256, laccum);
}

// Round 12
// 191.866 us; speedup vs baseline: 1.2726x; 1.2726x over previous
//
#include <hip/hip_runtime.h>
#include <hip/hip_bf16.h>
#include <hip/hip_fp16.h>
#include <hip/hip_fp8.h>

// DeformableAttention on MI355X.
// prep(weights^T bf16) -> build_rpe8(global fp8 quad table) -> gemm_bf16(q)
// -> fused conv+LN+GELU+pos+sample (v11: BRANCH-FREE taps: clamp+mask ->
// all loads hoistable/co-outstanding) -> gemm_bf16(kv) -> fused flash-attn
// (v9 proven body; rpe8 staged by coalesced copy from prebuilt table) ->
// gemm_bf16(out,+bias)

#define EPS_ 1e-5f
#define ASCALE 0.17677669529663687f      // 1/sqrt(32)
#define LOG2E  1.4426950408889634f

typedef __attribute__((ext_vector_type(8))) short bf16x8;
typedef __attribute__((ext_vector_type(4))) float f32x4;

__device__ __forceinline__ short f2bf(float f) {
  union { float f; unsigned u; } v; v.f = f;
  unsigned r = (v.u + 0x7fffu + ((v.u >> 16) & 1u)) >> 16;  // RNE
  return (short)r;
}
__device__ __forceinline__ unsigned pk2bf(float a, float b) {
  union { __hip_bfloat162 h; unsigned u; } v;
  v.h = __float22bfloat162_rn(make_float2(a, b));
  return v.u;
}
__device__ __forceinline__ float exp2_fast(float x) {
  return __builtin_amdgcn_exp2f(x);
}

// fp8 e4m3 quad pack/unpack: HW v_cvt_pk_* on gfx950, sw fallback otherwise.
__device__ __forceinline__ unsigned pack_fp8_quad(float v00, float v10,
                                                  float v01, float v11) {
#if __has_builtin(__builtin_amdgcn_cvt_pk_fp8_f32)
  int r = 0;
  r = __builtin_amdgcn_cvt_pk_fp8_f32(v00, v10, r, false);  // bytes 0,1
  r = __builtin_amdgcn_cvt_pk_fp8_f32(v01, v11, r, true);   // bytes 2,3
  return (unsigned)r;
#else
  __hip_fp8x2_e4m3 elo(make_float2(v00, v10));
  __hip_fp8x2_e4m3 ehi(make_float2(v01, v11));
  return (unsigned)(unsigned short)elo.__x |
         ((unsigned)(unsigned short)ehi.__x << 16);
#endif
}
__device__ __forceinline__ void unpack_fp8_quad(unsigned u, float& g00,
                                                float& g10, float& g01,
                                                float& g11) {
#if __has_builtin(__builtin_amdgcn_cvt_pk_f32_fp8)
  auto ga = __builtin_amdgcn_cvt_pk_f32_fp8((int)u, false);  // (v00, v10)
  auto gb = __builtin_amdgcn_cvt_pk_f32_fp8((int)u, true);   // (v01, v11)
  g00 = ga[0]; g10 = ga[1]; g01 = gb[0]; g11 = gb[1];
#else
  __hip_fp8x2_e4m3 plo, phi;
  plo.__x = (__hip_fp8x2_storage_t)(unsigned short)(u & 0xffffu);
  phi.__x = (__hip_fp8x2_storage_t)(unsigned short)(u >> 16);
  float2 fa = (float2)plo, fb = (float2)phi;
  g00 = fa.x; g10 = fa.y; g01 = fb.x; g11 = fb.y;
#endif
}

// ---------------------------------------------------------------------------
// Weight prep: Wkvt[n][k]=bf16(Wkv[k][n]); Woutt, Wqt likewise.
// ---------------------------------------------------------------------------
__global__ __launch_bounds__(256) void prep_weights(
    const float* __restrict__ Wkv, const float* __restrict__ Wout,
    const float* __restrict__ Wq, short* __restrict__ Wkvt,
    short* __restrict__ Woutt, short* __restrict__ Wqt)
{
  int bid = blockIdx.x, k = threadIdx.x;
  if (bid < 512) Wkvt[bid * 256 + k] = f2bf(Wkv[k * 512 + bid]);
  else if (bid < 768) { int n = bid - 512; Woutt[n * 256 + k] = f2bf(Wout[k * 256 + n]); }
  else { int n = bid - 768; Wqt[n * 256 + k] = f2bf(Wq[k * 256 + n]); }
}

// ---------------------------------------------------------------------------
// Build the fp8 rpe quad table ONCE per head into global (8 x 64 x 64 u32).
// ---------------------------------------------------------------------------
__global__ __launch_bounds__(256) void build_rpe8(
    const float* __restrict__ rpe, unsigned* __restrict__ rpeq)
{
  int i = blockIdx.x * 256 + threadIdx.x;   // 0..32767
  int h = i >> 12, idx = i & 4095;
  int ty = idx >> 6, tx = idx & 63;
  const float* rp = rpe + h * 3969;
  float v00 = 0.f, v10 = 0.f, v01 = 0.f, v11 = 0.f;
  if (tx <= 62) {
    if (ty <= 62) v00 = rp[ty * 63 + tx] * LOG2E;
    if (ty <= 61) v10 = rp[(ty + 1) * 63 + tx] * LOG2E;
  }
  if (tx <= 61) {
    if (ty <= 62) v01 = rp[ty * 63 + tx + 1] * LOG2E;
    if (ty <= 61) v11 = rp[(ty + 1) * 63 + tx + 1] * LOG2E;
  }
  rpeq[i] = pack_fp8_quad(v00, v10, v01, v11);
}

// ---------------------------------------------------------------------------
// bf16 MFMA GEMM: C[M,N] = A[M,256] @ Bt[N,256]^T (+bias), with prefetch.
// ---------------------------------------------------------------------------
__global__ __launch_bounds__(256) void gemm_bf16(
    const short* __restrict__ Ab, const float* __restrict__ Af,
    const short* __restrict__ Bt,
    float* __restrict__ Cf, short* __restrict__ Cb,
    const float* __restrict__ bias, int N)
{
  __shared__ __align__(16) short As[64 * 40];
  __shared__ __align__(16) short Bs[64 * 40];
  const int t = threadIdx.x;
  const int n0 = blockIdx.x << 6, m0 = blockIdx.y << 6;
  const int wv = t >> 6, l16 = t & 15, quad = (t & 63) >> 4;
  const int row = t >> 2, koff = (t & 3) << 3;

  auto loadA = [&](int k0) -> bf16x8 {
    if (Af) {
      const float* src = &Af[(size_t)(m0 + row) * 256 + k0 + koff];
      float4 f0 = *(const float4*)src;
      float4 f1 = *(const float4*)(src + 4);
      union { unsigned u[4]; bf16x8 v; } c;
      c.u[0] = pk2bf(f0.x, f0.y); c.u[1] = pk2bf(f0.z, f0.w);
      c.u[2] = pk2bf(f1.x, f1.y); c.u[3] = pk2bf(f1.z, f1.w);
      return c.v;
    }
    return *(const bf16x8*)&Ab[(size_t)(m0 + row) * 256 + k0 + koff];
  };

  f32x4 acc[4] = {};
  bf16x8 av = loadA(0);
  bf16x8 bv = *(const bf16x8*)&Bt[(size_t)(n0 + row) * 256 + koff];
  for (int k0 = 0; k0 < 256; k0 += 32) {
    __syncthreads();  // prior-iter frag reads done before overwrite
    *(bf16x8*)&As[row * 40 + koff] = av;
    *(bf16x8*)&Bs[row * 40 + koff] = bv;
    __syncthreads();
    if (k0 + 32 < 256) {  // prefetch next chunk before MFMA section
      av = loadA(k0 + 32);
      bv = *(const bf16x8*)&Bt[(size_t)(n0 + row) * 256 + k0 + 32 + koff];
    }
    bf16x8 a = *(const bf16x8*)&As[((wv << 4) + l16) * 40 + (quad << 3)];
#pragma unroll
    for (int jt = 0; jt < 4; jt++) {
      bf16x8 bb = *(const bf16x8*)&Bs[((jt << 4) + l16) * 40 + (quad << 3)];
      acc[jt] = __builtin_amdgcn_mfma_f32_16x16x32_bf16(a, bb, acc[jt], 0, 0, 0);
    }
  }
#pragma unroll
  for (int jt = 0; jt < 4; jt++) {
#pragma unroll
    for (int r = 0; r < 4; r++) {
      int mrow = m0 + (wv << 4) + (quad << 2) + r;
      int ncol = n0 + (jt << 4) + l16;
      float v = acc[jt][r];
      if (bias) v += bias[ncol];
      if (Cf) Cf[(size_t)mrow * N + ncol] = v;
      else    Cb[(size_t)mrow * N + ncol] = f2bf(v);
    }
  }
}

// ---------------------------------------------------------------------------
// Fused: conv5x5 depthwise + LN(128) + GELU + @Woff + tanh -> pos, then
// grid_sample of this pixel's group channels -> xs (bf16). Wave per (b,g,pix).
// v11: BRANCH-FREE taps.  OOB handled by clamped address + weightxmask
// (mask 0 -> tap contributes exactly 0; clamped address is always valid q).
// No control flow in the tap loops => compiler hoists/batches all loads.
// Weights preloaded to registers.
// ---------------------------------------------------------------------------
__global__ __launch_bounds__(256) void conv_pos_sample_kernel(
    const float* __restrict__ q, const float* __restrict__ conv_w,
    const float* __restrict__ conv_b, const float* __restrict__ ln_g,
    const float* __restrict__ ln_b, const float* __restrict__ Woff,
    float* __restrict__ pos, short* __restrict__ xsb)
{
  const int p = (blockIdx.x << 2) + (threadIdx.x >> 6);
  const int lane = threadIdx.x & 63;
  const int bg = p >> 10, pix = p & 1023;
  const int hh = pix >> 5, ww = pix & 31;
  const int b = bg >> 1, g = bg & 1;
  const int c0 = lane << 1;
  const float* qbase = q + ((size_t)(b << 10) << 8) + (g << 7) + c0;

  // preload 2x25 weights (unrolled, static idx -> registers)
  float wr0[25], wr1[25];
  {
    const float* w0 = conv_w + c0 * 25;
#pragma unroll
    for (int i = 0; i < 25; i++) { wr0[i] = w0[i]; wr1[i] = w0[i + 25]; }
  }

  float2 cb = *(const float2*)&conv_b[c0];
  float a0 = cb.x, a1 = cb.y;
#pragma unroll
  for (int dy = 0; dy < 5; dy++) {
    int y = hh + dy - 2;
    int yc = y < 0 ? 0 : (y > 31 ? 31 : y);
    float my = ((unsigned)y < 32u) ? 1.f : 0.f;
#pragma unroll
    for (int dx = 0; dx < 5; dx++) {
      int x = ww + dx - 2;
      int xc = x < 0 ? 0 : (x > 31 ? 31 : x);
      float m = ((unsigned)x < 32u) ? my : 0.f;
      float2 qv = *(const float2*)&qbase[(size_t)((yc << 5) + xc) << 8];
      a0 = fmaf(qv.x * m, wr0[dy * 5 + dx], a0);
      a1 = fmaf(qv.y * m, wr1[dy * 5 + dx], a1);
    }
  }
  float s1 = a0 + a1, s2 = a0 * a0 + a1 * a1;
#pragma unroll
  for (int o = 32; o; o >>= 1) { s1 += __shfl_xor(s1, o); s2 += __shfl_xor(s2, o); }
  float mu = s1 * (1.f / 128.f);
  float inv = rsqrtf(fmaf(-mu, mu, s2 * (1.f / 128.f)) + EPS_);
  float2 lg = *(const float2*)&ln_g[c0];
  float2 lb = *(const float2*)&ln_b[c0];
  float v0 = (a0 - mu) * inv * lg.x + lb.x;
  float v1 = (a1 - mu) * inv * lg.y + lb.y;
  float ge0 = 0.5f * v0 * (1.f + erff(v0 * 0.70710678118654752f));
  float ge1 = 0.5f * v1 * (1.f + erff(v1 * 0.70710678118654752f));
  float2 W0 = *(const float2*)&Woff[c0 * 2];
  float2 W1 = *(const float2*)&Woff[c0 * 2 + 2];
  float o0 = ge0 * W0.x + ge1 * W1.x;
  float o1 = ge0 * W0.y + ge1 * W1.y;
#pragma unroll
  for (int o = 32; o; o >>= 1) { o0 += __shfl_xor(o0, o); o1 += __shfl_xor(o1, o); }
  float py = tanhf(o0) * 0.0625f + ((hh + 0.5f) * 0.0625f - 1.f);
  float px = tanhf(o1) * 0.0625f + ((ww + 0.5f) * 0.0625f - 1.f);
  if (lane == 0)
    ((float2*)pos)[(bg << 10) + pix] = make_float2(py, px);

  float x = (px + 1.f) * 15.5f;
  float y = (py + 1.f) * 15.5f;
  float x0f = floorf(x), y0f = floorf(y);
  int ix0 = (int)x0f, iy0 = (int)y0f;
  float fx = x - x0f, fy = y - y0f;
  float ac0 = 0.f, ac1 = 0.f;
#pragma unroll
  for (int dy = 0; dy < 2; dy++) {
#pragma unroll
    for (int dx = 0; dx < 2; dx++) {
      int yi = iy0 + dy, xi = ix0 + dx;
      int yc = yi < 0 ? 0 : (yi > 31 ? 31 : yi);
      int xc = xi < 0 ? 0 : (xi > 31 ? 31 : xi);
      float valid = ((unsigned)yi < 32u && (unsigned)xi < 32u) ? 1.f : 0.f;
      float w = (dy ? fy : 1.f - fy) * (dx ? fx : 1.f - fx) * valid;
      float2 qv = *(const float2*)&qbase[(size_t)((yc << 5) + xc) << 8];
      ac0 = fmaf(w, qv.x, ac0);
      ac1 = fmaf(w, qv.y, ac1);
    }
  }
  *(unsigned*)&xsb[(size_t)((b << 10) + pix) * 256 + (g << 7) + c0] = pk2bf(ac0, ac1);
}

// ---------------------------------------------------------------------------
// Fused attention (v9 proven body; rpe8 staged by coalesced copy from the
// prebuilt global rpeq table).  One block = (64-row i-tile, head, batch),
// grid 1024, ~30 KB LDS -> 4 blocks/CU.  K/Q direct from global; V
// cooperatively LDS-staged; wave-local P; fixed-m softmax, l via ones-MFMA.
// ---------------------------------------------------------------------------
__global__ __launch_bounds__(256, 4) void attn_kernel(
    const float* __restrict__ q, const short* __restrict__ kvb,
    const float* __restrict__ pos, const unsigned* __restrict__ rpeq,
    short* __restrict__ ao)
{
  const int it = blockIdx.x, h = blockIdx.y, b = blockIdx.z;
  const int g = h >> 2, t = threadIdx.x;
  const int wv = t >> 6, l16 = t & 15, quad = (t & 63) >> 4;

  __shared__ __align__(16) short PL[64 * 72];     // P (wave-local rows)
  __shared__ __align__(16) short Vt[32 * 68];     // V^T [d][j]
  __shared__ float2 posT[64];                     // (-15.5*py, -15.5*px)
  __shared__ __align__(16) unsigned rpe8[64 * 64];  // fp8 quad per point

  // ---- stage fp8 rpe quad table: coalesced copy from prebuilt rpeq
  {
    const unsigned* src = rpeq + (h << 12);
    for (int i = t; i < 4096; i += 256) rpe8[i] = src[i];
  }

  // ---- Q A-frag from global (once), scaled by ASCALE*LOG2E
  const int row0 = (it << 6) + (wv << 4);
  bf16x8 aq;
  {
    const float* src = q + (size_t)((b << 10) + row0 + l16) * 256 + (h << 5) + (quad << 3);
    float4 f0 = *(const float4*)src;
    float4 f1 = *(const float4*)(src + 4);
    const float sc = ASCALE * LOG2E;
    union { unsigned u[4]; bf16x8 v; } c;
    c.u[0] = pk2bf(f0.x * sc, f0.y * sc); c.u[1] = pk2bf(f0.z * sc, f0.w * sc);
    c.u[2] = pk2bf(f1.x * sc, f1.y * sc); c.u[3] = pk2bf(f1.z * sc, f1.w * sc);
    aq = c.v;
  }

  // sampling coords (origin +31): wave's 16 rows share one raster row
  const float ayc = 15.5f * (((row0 >> 5) + 0.5f) * 0.0625f - 1.f) + 31.f;
  float ax[4];
#pragma unroll
  for (int r = 0; r < 4; r++) {
    int ix = (row0 & 31) + (quad << 2) + r;
    ax[r] = 15.5f * ((ix + 0.5f) * 0.0625f - 1.f) + 31.f;
  }

  bf16x8 vones;
#pragma unroll
  for (int i = 0; i < 8; i++) vones[i] = (short)0x3F80;  // bf16 1.0

  // ---- strength-reduced pointer bases (advance by constants per kt)
  const int vj = t & 63, vc = t >> 6;
  const short* vsrc = kvb + (size_t)((b << 10) + vj) * 512 + 256 + (h << 5) + (vc << 3);
  const short* ksrc = kvb + (size_t)((b << 10) + l16) * 512 + (h << 5) + (quad << 3);
  const float2* psrc = (const float2*)pos + (((b << 1) + g) << 10) + t;

  f32x4 Oacc[2] = {};
  f32x4 lacc = {};

  for (int kt = 0; kt < 16; kt++) {
    __syncthreads();  // [b1] prior PV reads done (covers rpe8 copy at kt=0)
    // ---- stage V^T: thread (j = t&63, c = t>>6) -> d = c*8..c*8+7
    {
      bf16x8 vv = *(const bf16x8*)vsrc;
#pragma unroll
      for (int k2 = 0; k2 < 8; k2++) Vt[((vc << 3) + k2) * 68 + vj] = vv[k2];
    }
    if (t < 64) {
      float2 pp = *psrc;
      posT[t] = make_float2(-15.5f * pp.x, -15.5f * pp.y);
    }
    __syncthreads();  // [b2]

    // ---- QK^T first: 4 K B-frags from global (L1) + 4 MFMA, before bias
    f32x4 S[4];
#pragma unroll
    for (int jt = 0; jt < 4; jt++) {
      bf16x8 bk = *(const bf16x8*)(ksrc + (size_t)jt * 8192);
      f32x4 z = {};
      S[jt] = __builtin_amdgcn_mfma_f32_16x16x32_bf16(aq, bk, z, 0, 0, 0);
    }

    // ---- y-chains for the 4 j's (posT broadcast reads), hoisted
    float fyv[4];
    int ybv[4];
    float wyv[4];
#pragma unroll
    for (int jt = 0; jt < 4; jt++) {
      float2 bv = posT[(jt << 4) + l16];
      float ys = ayc + bv.x;
      float y0f = floorf(ys);
      fyv[jt] = ys - y0f;
      ybv[jt] = (int)y0f << 6;
      wyv[jt] = bv.y;
    }

    // ---- bias sample + p = exp2(S+bias), per jt
    unsigned pu[4][2];
#pragma unroll
    for (int jt = 0; jt < 4; jt++) {
      float fy = fyv[jt];
      int ybase = ybv[jt];
      float pv[4];
#pragma unroll
      for (int r = 0; r < 4; r++) {
        float sx = ax[r] + wyv[jt];
        float x0f = floorf(sx);
        float fx = sx - x0f;
        unsigned u = rpe8[ybase + (int)x0f];
        float g00, g10, g01, g11;
        unpack_fp8_quad(u, g00, g10, g01, g11);
        float h0 = fmaf(fx, g01 - g00, g00);
        float h1 = fmaf(fx, g11 - g10, g10);
        float bias = fmaf(fy, h1 - h0, h0);
        pv[r] = exp2_fast(S[jt][r] + bias);
      }
      pu[jt][0] = pk2bf(pv[0], pv[1]);
      pu[jt][1] = pk2bf(pv[2], pv[3]);
    }

    // ---- wave-local P write -> A-frag read -> PV + l (no barrier)
#pragma unroll
    for (int jt = 0; jt < 4; jt++) {
      int cb = (jt << 4) + l16;
      int rb = ((wv << 4) + (quad << 2)) * 72 + cb;
      PL[rb]       = (short)(pu[jt][0] & 0xffff);
      PL[rb + 72]  = (short)(pu[jt][0] >> 16);
      PL[rb + 144] = (short)(pu[jt][1] & 0xffff);
      PL[rb + 216] = (short)(pu[jt][1] >> 16);
    }
    bf16x8 pa0 = *(const bf16x8*)&PL[((wv << 4) + l16) * 72 + (quad << 3)];
    bf16x8 pa1 = *(const bf16x8*)&PL[((wv << 4) + l16) * 72 + 32 + (quad << 3)];
#pragma unroll
    for (int dt = 0; dt < 2; dt++) {
      bf16x8 vb0 = *(const bf16x8*)&Vt[((dt << 4) + l16) * 68 + (quad << 3)];
      bf16x8 vb1 = *(const bf16x8*)&Vt[((dt << 4) + l16) * 68 + 32 + (quad << 3)];
      Oacc[dt] = __builtin_amdgcn_mfma_f32_16x16x32_bf16(pa0, vb0, Oacc[dt], 0, 0, 0);
      Oacc[dt] = __builtin_amdgcn_mfma_f32_16x16x32_bf16(pa1, vb1, Oacc[dt], 0, 0, 0);
    }
    lacc = __builtin_amdgcn_mfma_f32_16x16x32_bf16(pa0, vones, lacc, 0, 0, 0);
    lacc = __builtin_amdgcn_mfma_f32_16x16x32_bf16(pa1, vones, lacc, 0, 0, 0);

    // advance strength-reduced pointers (64 rows * 512 shorts; 64 float2)
    vsrc += 32768; ksrc += 32768; psrc += 64;
  }

  // ---- epilogue -> ao bf16
#pragma unroll
  for (int r = 0; r < 4; r++) {
    float inv = 1.f / lacc[r];
    int row = row0 + (quad << 2) + r;
#pragma unroll
    for (int dt = 0; dt < 2; dt++) {
      ao[(size_t)((b << 10) + row) * 256 + (h << 5) + (dt << 4) + l16] =
          f2bf(Oacc[dt][r] * inv);
    }
  }
}

// ---------------------------------------------------------------------------
extern "C" void kernel_launch(void* const* d_in, const int* in_sizes, int n_in,
                              void* d_out, int out_size, void* d_ws, size_t ws_size,
                              hipStream_t stream) {
  (void)in_sizes; (void)n_in; (void)out_size; (void)ws_size;
  const float* x      = (const float*)d_in[0];
  const float* Wq     = (const float*)d_in[1];
  const float* Wkv    = (const float*)d_in[2];
  const float* conv_w = (const float*)d_in[3];
  const float* conv_b = (const float*)d_in[4];
  const float* ln_g   = (const float*)d_in[5];
  const float* ln_b   = (const float*)d_in[6];
  const float* Woff   = (const float*)d_in[7];
  const float* rpe    = (const float*)d_in[8];
  const float* Wout   = (const float*)d_in[9];
  const float* bout   = (const float*)d_in[10];
  float* out = (float*)d_out;

  float* ws      = (float*)d_ws;
  float* q       = ws;                        // [0 .. 2097152)
  float* pos     = ws + 2097152;              // [.. 2129920)
  short* kvb     = (short*)(ws + 2129920);    // 8192*512 bf16 = 2,097,152 f32 [.. 4227072)
  short* xsb     = (short*)(ws + 4227072);    // 8192*256 bf16 = 1,048,576 f32 [.. 5275648)
  short* aob     = (short*)(ws + 5275648);    // 8192*256 bf16 = 1,048,576 f32 [.. 6324224)
  short* Wkvt    = (short*)(ws + 6324224);    // 512*256 bf16  =    65,536 f32 [.. 6389760)
  short* Woutt   = (short*)(ws + 6389760);    // 256*256 bf16  =    32,768 f32 [.. 6422528)
  short* Wqt     = (short*)(ws + 6422528);    // 256*256 bf16  =    32,768 f32 [.. 6455296)
  unsigned* rpeq = (unsigned*)(ws + 6455296); // 8*4096 u32    =    32,768 f32 [.. 6488064)
  // total 6,488,064 f32 = 26.0 MB

  prep_weights<<<1024, 256, 0, stream>>>(Wkv, Wout, Wq, Wkvt, Woutt, Wqt);
  // 0b. build the global fp8 rpe quad table (once per head)
  build_rpe8<<<128, 256, 0, stream>>>(rpe, rpeq);
  // 1. q = x @ Wq (bf16 MFMA, f32 A staged+converted, f32 out)
  gemm_bf16<<<dim3(4, 128), 256, 0, stream>>>(nullptr, x, Wqt, q, nullptr, nullptr, 256);
  // 2+3. conv + LN + GELU + Woff + tanh -> pos, fused grid_sample -> xs
  conv_pos_sample_kernel<<<4096, 256, 0, stream>>>(q, conv_w, conv_b, ln_g, ln_b,
                                                   Woff, pos, xsb);
  // 4. kv = xs @ Wkv (bf16 MFMA, bf16 out)
  gemm_bf16<<<dim3(8, 128), 256, 0, stream>>>(xsb, nullptr, Wkvt, nullptr, kvb, nullptr, 512);
  // 5. fused attention (v9 body + rpeq copy) -> ao (bf16)
  attn_kernel<<<dim3(16, 8, 8), 256, 0, stream>>>(q, kvb, pos, rpeq, aob);
  // 6. out = ao @ Wout + bout (bf16 MFMA, f32 out)
  gemm_bf16<<<dim3(4, 128), 256, 0, stream>>>(aob, nullptr, Woutt, out, nullptr, bout, 256);
}

// Round 16
// 187.179 us; speedup vs baseline: 1.3045x; 1.0250x over previous
//
#include <hip/hip_runtime.h>
#include <hip/hip_bf16.h>
#include <hip/hip_fp16.h>
#include <hip/hip_fp8.h>

// DeformableAttention on MI355X.
// prep_all(weights^T bf16 + global fp8 rpe quad table) -> gemm_bf16(q) ->
// fused conv+LN+GELU+pos+sample (branch-free taps) -> gemm_bf16(kv) ->
// fused flash-attn v13c (v12's exact math + cross-kt V/pos register
// prefetch pinned with asm) -> gemm_bf16(out,+bias)
// v13/v13b BUG (identical absmax 2.59e-4 in both): the restructure dropped
// `ksrc += 32768` -- QK^T read kt=0's K rows for all 16 kt.  v13c restores
// the advance at the loop tail.  Micro-opts stay reverted (exonerated but
// worthless).

#define EPS_ 1e-5f
#define ASCALE 0.17677669529663687f      // 1/sqrt(32)
#define LOG2E  1.4426950408889634f

typedef __attribute__((ext_vector_type(8))) short bf16x8;
typedef __attribute__((ext_vector_type(4))) float f32x4;

__device__ __forceinline__ short f2bf(float f) {
  union { float f; unsigned u; } v; v.f = f;
  unsigned r = (v.u + 0x7fffu + ((v.u >> 16) & 1u)) >> 16;  // RNE
  return (short)r;
}
__device__ __forceinline__ unsigned pk2bf(float a, float b) {
  union { __hip_bfloat162 h; unsigned u; } v;
  v.h = __float22bfloat162_rn(make_float2(a, b));
  return v.u;
}
__device__ __forceinline__ float exp2_fast(float x) {
  return __builtin_amdgcn_exp2f(x);
}

// fp8 e4m3 quad pack/unpack: HW v_cvt_pk_* on gfx950, sw fallback otherwise.
__device__ __forceinline__ unsigned pack_fp8_quad(float v00, float v10,
                                                  float v01, float v11) {
#if __has_builtin(__builtin_amdgcn_cvt_pk_fp8_f32)
  int r = 0;
  r = __builtin_amdgcn_cvt_pk_fp8_f32(v00, v10, r, false);  // bytes 0,1
  r = __builtin_amdgcn_cvt_pk_fp8_f32(v01, v11, r, true);   // bytes 2,3
  return (unsigned)r;
#else
  __hip_fp8x2_e4m3 elo(make_float2(v00, v10));
  __hip_fp8x2_e4m3 ehi(make_float2(v01, v11));
  return (unsigned)(unsigned short)elo.__x |
         ((unsigned)(unsigned short)ehi.__x << 16);
#endif
}
__device__ __forceinline__ void unpack_fp8_quad(unsigned u, float& g00,
                                                float& g10, float& g01,
                                                float& g11) {
#if __has_builtin(__builtin_amdgcn_cvt_pk_f32_fp8)
  auto ga = __builtin_amdgcn_cvt_pk_f32_fp8((int)u, false);  // (v00, v10)
  auto gb = __builtin_amdgcn_cvt_pk_f32_fp8((int)u, true);   // (v01, v11)
  g00 = ga[0]; g10 = ga[1]; g01 = gb[0]; g11 = gb[1];
#else
  __hip_fp8x2_e4m3 plo, phi;
  plo.__x = (__hip_fp8x2_storage_t)(unsigned short)(u & 0xffffu);
  phi.__x = (__hip_fp8x2_storage_t)(unsigned short)(u >> 16);
  float2 fa = (float2)plo, fb = (float2)phi;
  g00 = fa.x; g10 = fa.y; g01 = fb.x; g11 = fb.y;
#endif
}

// ---------------------------------------------------------------------------
// Prep: bids [0,1024) weight transposes; bids [1024,1152) build the global
// fp8 rpe quad table (8 x 64 x 64 u32), once per head.
// ---------------------------------------------------------------------------
__global__ __launch_bounds__(256) void prep_all(
    const float* __restrict__ Wkv, const float* __restrict__ Wout,
    const float* __restrict__ Wq, const float* __restrict__ rpe,
    short* __restrict__ Wkvt, short* __restrict__ Woutt,
    short* __restrict__ Wqt, unsigned* __restrict__ rpeq)
{
  int bid = blockIdx.x, k = threadIdx.x;
  if (bid >= 1024) {
    int i = (bid - 1024) * 256 + k;   // 0..32767
    int h = i >> 12, idx = i & 4095;
    int ty = idx >> 6, tx = idx & 63;
    const float* rp = rpe + h * 3969;
    float v00 = 0.f, v10 = 0.f, v01 = 0.f, v11 = 0.f;
    if (tx <= 62) {
      if (ty <= 62) v00 = rp[ty * 63 + tx] * LOG2E;
      if (ty <= 61) v10 = rp[(ty + 1) * 63 + tx] * LOG2E;
    }
    if (tx <= 61) {
      if (ty <= 62) v01 = rp[ty * 63 + tx + 1] * LOG2E;
      if (ty <= 61) v11 = rp[(ty + 1) * 63 + tx + 1] * LOG2E;
    }
    rpeq[i] = pack_fp8_quad(v00, v10, v01, v11);
    return;
  }
  if (bid < 512) Wkvt[bid * 256 + k] = f2bf(Wkv[k * 512 + bid]);
  else if (bid < 768) { int n = bid - 512; Woutt[n * 256 + k] = f2bf(Wout[k * 256 + n]); }
  else { int n = bid - 768; Wqt[n * 256 + k] = f2bf(Wq[k * 256 + n]); }
}

// ---------------------------------------------------------------------------
// bf16 MFMA GEMM: C[M,N] = A[M,256] @ Bt[N,256]^T (+bias), with prefetch.
// ---------------------------------------------------------------------------
__global__ __launch_bounds__(256) void gemm_bf16(
    const short* __restrict__ Ab, const float* __restrict__ Af,
    const short* __restrict__ Bt,
    float* __restrict__ Cf, short* __restrict__ Cb,
    const float* __restrict__ bias, int N)
{
  __shared__ __align__(16) short As[64 * 40];
  __shared__ __align__(16) short Bs[64 * 40];
  const int t = threadIdx.x;
  const int n0 = blockIdx.x << 6, m0 = blockIdx.y << 6;
  const int wv = t >> 6, l16 = t & 15, quad = (t & 63) >> 4;
  const int row = t >> 2, koff = (t & 3) << 3;

  auto loadA = [&](int k0) -> bf16x8 {
    if (Af) {
      const float* src = &Af[(size_t)(m0 + row) * 256 + k0 + koff];
      float4 f0 = *(const float4*)src;
      float4 f1 = *(const float4*)(src + 4);
      union { unsigned u[4]; bf16x8 v; } c;
      c.u[0] = pk2bf(f0.x, f0.y); c.u[1] = pk2bf(f0.z, f0.w);
      c.u[2] = pk2bf(f1.x, f1.y); c.u[3] = pk2bf(f1.z, f1.w);
      return c.v;
    }
    return *(const bf16x8*)&Ab[(size_t)(m0 + row) * 256 + k0 + koff];
  };

  f32x4 acc[4] = {};
  bf16x8 av = loadA(0);
  bf16x8 bv = *(const bf16x8*)&Bt[(size_t)(n0 + row) * 256 + koff];
  for (int k0 = 0; k0 < 256; k0 += 32) {
    __syncthreads();  // prior-iter frag reads done before overwrite
    *(bf16x8*)&As[row * 40 + koff] = av;
    *(bf16x8*)&Bs[row * 40 + koff] = bv;
    __syncthreads();
    if (k0 + 32 < 256) {  // prefetch next chunk before MFMA section
      av = loadA(k0 + 32);
      bv = *(const bf16x8*)&Bt[(size_t)(n0 + row) * 256 + k0 + 32 + koff];
    }
    bf16x8 a = *(const bf16x8*)&As[((wv << 4) + l16) * 40 + (quad << 3)];
#pragma unroll
    for (int jt = 0; jt < 4; jt++) {
      bf16x8 bb = *(const bf16x8*)&Bs[((jt << 4) + l16) * 40 + (quad << 3)];
      acc[jt] = __builtin_amdgcn_mfma_f32_16x16x32_bf16(a, bb, acc[jt], 0, 0, 0);
    }
  }
#pragma unroll
  for (int jt = 0; jt < 4; jt++) {
#pragma unroll
    for (int r = 0; r < 4; r++) {
      int mrow = m0 + (wv << 4) + (quad << 2) + r;
      int ncol = n0 + (jt << 4) + l16;
      float v = acc[jt][r];
      if (bias) v += bias[ncol];
      if (Cf) Cf[(size_t)mrow * N + ncol] = v;
      else    Cb[(size_t)mrow * N + ncol] = f2bf(v);
    }
  }
}

// ---------------------------------------------------------------------------
// Fused: conv5x5 depthwise + LN(128) + GELU + @Woff + tanh -> pos, then
// grid_sample of this pixel's group channels -> xs (bf16). Wave per (b,g,pix).
// Branch-free taps (clamp + weight*mask); weights preloaded to registers.
// ---------------------------------------------------------------------------
__global__ __launch_bounds__(256) void conv_pos_sample_kernel(
    const float* __restrict__ q, const float* __restrict__ conv_w,
    const float* __restrict__ conv_b, const float* __restrict__ ln_g,
    const float* __restrict__ ln_b, const float* __restrict__ Woff,
    float* __restrict__ pos, short* __restrict__ xsb)
{
  const int p = (blockIdx.x << 2) + (threadIdx.x >> 6);
  const int lane = threadIdx.x & 63;
  const int bg = p >> 10, pix = p & 1023;
  const int hh = pix >> 5, ww = pix & 31;
  const int b = bg >> 1, g = bg & 1;
  const int c0 = lane << 1;
  const float* qbase = q + ((size_t)(b << 10) << 8) + (g << 7) + c0;

  float wr0[25], wr1[25];
  {
    const float* w0 = conv_w + c0 * 25;
#pragma unroll
    for (int i = 0; i < 25; i++) { wr0[i] = w0[i]; wr1[i] = w0[i + 25]; }
  }

  float2 cb = *(const float2*)&conv_b[c0];
  float a0 = cb.x, a1 = cb.y;
#pragma unroll
  for (int dy = 0; dy < 5; dy++) {
    int y = hh + dy - 2;
    int yc = y < 0 ? 0 : (y > 31 ? 31 : y);
    float my = ((unsigned)y < 32u) ? 1.f : 0.f;
#pragma unroll
    for (int dx = 0; dx < 5; dx++) {
      int x = ww + dx - 2;
      int xc = x < 0 ? 0 : (x > 31 ? 31 : x);
      float m = ((unsigned)x < 32u) ? my : 0.f;
      float2 qv = *(const float2*)&qbase[(size_t)((yc << 5) + xc) << 8];
      a0 = fmaf(qv.x * m, wr0[dy * 5 + dx], a0);
      a1 = fmaf(qv.y * m, wr1[dy * 5 + dx], a1);
    }
  }
  float s1 = a0 + a1, s2 = a0 * a0 + a1 * a1;
#pragma unroll
  for (int o = 32; o; o >>= 1) { s1 += __shfl_xor(s1, o); s2 += __shfl_xor(s2, o); }
  float mu = s1 * (1.f / 128.f);
  float inv = rsqrtf(fmaf(-mu, mu, s2 * (1.f / 128.f)) + EPS_);
  float2 lg = *(const float2*)&ln_g[c0];
  float2 lb = *(const float2*)&ln_b[c0];
  float v0 = (a0 - mu) * inv * lg.x + lb.x;
  float v1 = (a1 - mu) * inv * lg.y + lb.y;
  float ge0 = 0.5f * v0 * (1.f + erff(v0 * 0.70710678118654752f));
  float ge1 = 0.5f * v1 * (1.f + erff(v1 * 0.70710678118654752f));
  float2 W0 = *(const float2*)&Woff[c0 * 2];
  float2 W1 = *(const float2*)&Woff[c0 * 2 + 2];
  float o0 = ge0 * W0.x + ge1 * W1.x;
  float o1 = ge0 * W0.y + ge1 * W1.y;
#pragma unroll
  for (int o = 32; o; o >>= 1) { o0 += __shfl_xor(o0, o); o1 += __shfl_xor(o1, o); }
  float py = tanhf(o0) * 0.0625f + ((hh + 0.5f) * 0.0625f - 1.f);
  float px = tanhf(o1) * 0.0625f + ((ww + 0.5f) * 0.0625f - 1.f);
  if (lane == 0)
    ((float2*)pos)[(bg << 10) + pix] = make_float2(py, px);

  float x = (px + 1.f) * 15.5f;
  float y = (py + 1.f) * 15.5f;
  float x0f = floorf(x), y0f = floorf(y);
  int ix0 = (int)x0f, iy0 = (int)y0f;
  float fx = x - x0f, fy = y - y0f;
  float ac0 = 0.f, ac1 = 0.f;
#pragma unroll
  for (int dy = 0; dy < 2; dy++) {
#pragma unroll
    for (int dx = 0; dx < 2; dx++) {
      int yi = iy0 + dy, xi = ix0 + dx;
      int yc = yi < 0 ? 0 : (yi > 31 ? 31 : yi);
      int xc = xi < 0 ? 0 : (xi > 31 ? 31 : xi);
      float valid = ((unsigned)yi < 32u && (unsigned)xi < 32u) ? 1.f : 0.f;
      float w = (dy ? fy : 1.f - fy) * (dx ? fx : 1.f - fx) * valid;
      float2 qv = *(const float2*)&qbase[(size_t)((yc << 5) + xc) << 8];
      ac0 = fmaf(w, qv.x, ac0);
      ac1 = fmaf(w, qv.y, ac1);
    }
  }
  *(unsigned*)&xsb[(size_t)((b << 10) + pix) * 256 + (g << 7) + c0] = pk2bf(ac0, ac1);
}

// ---------------------------------------------------------------------------
// Fused attention v13c = v12's exact body/math + cross-kt V/pos register
// prefetch (asm-pinned) + THE FIX: ksrc advances every kt (v13/v13b dropped
// it).  One block = (64-row i-tile, head, batch), grid 1024, ~30 KB LDS ->
// 4 blocks/CU.  K/Q direct from global; V cooperatively LDS-staged;
// wave-local P; fixed-m softmax, l via ones-MFMA.
// ---------------------------------------------------------------------------
__global__ __launch_bounds__(256, 4) void attn_kernel(
    const float* __restrict__ q, const short* __restrict__ kvb,
    const float* __restrict__ pos, const unsigned* __restrict__ rpeq,
    short* __restrict__ ao)
{
  const int it = blockIdx.x, h = blockIdx.y, b = blockIdx.z;
  const int g = h >> 2, t = threadIdx.x;
  const int wv = t >> 6, l16 = t & 15, quad = (t & 63) >> 4;

  __shared__ __align__(16) short PL[64 * 72];     // P (wave-local rows)
  __shared__ __align__(16) short Vt[32 * 68];     // V^T [d][j]
  __shared__ float2 posT[64];                     // (-15.5*py, -15.5*px)
  __shared__ __align__(16) unsigned rpe8[64 * 64];  // fp8 quad per point

  // ---- stage fp8 rpe quad table: coalesced copy from prebuilt rpeq
  {
    const unsigned* src = rpeq + (h << 12);
    for (int i = t; i < 4096; i += 256) rpe8[i] = src[i];
  }

  // ---- Q A-frag from global (once), scaled by ASCALE*LOG2E
  const int row0 = (it << 6) + (wv << 4);
  bf16x8 aq;
  {
    const float* src = q + (size_t)((b << 10) + row0 + l16) * 256 + (h << 5) + (quad << 3);
    float4 f0 = *(const float4*)src;
    float4 f1 = *(const float4*)(src + 4);
    const float sc = ASCALE * LOG2E;
    union { unsigned u[4]; bf16x8 v; } c;
    c.u[0] = pk2bf(f0.x * sc, f0.y * sc); c.u[1] = pk2bf(f0.z * sc, f0.w * sc);
    c.u[2] = pk2bf(f1.x * sc, f1.y * sc); c.u[3] = pk2bf(f1.z * sc, f1.w * sc);
    aq = c.v;
  }

  // sampling coords (origin +31): wave's 16 rows share one raster row
  const float ayc = 15.5f * (((row0 >> 5) + 0.5f) * 0.0625f - 1.f) + 31.f;
  float ax[4];
#pragma unroll
  for (int r = 0; r < 4; r++) {
    int ix = (row0 & 31) + (quad << 2) + r;
    ax[r] = 15.5f * ((ix + 0.5f) * 0.0625f - 1.f) + 31.f;
  }

  bf16x8 vones;
#pragma unroll
  for (int i = 0; i < 8; i++) vones[i] = (short)0x3F80;  // bf16 1.0

  // ---- strength-reduced pointer bases (advance by constants per kt)
  const int vj = t & 63, vc = t >> 6;
  const short* vsrc = kvb + (size_t)((b << 10) + vj) * 512 + 256 + (h << 5) + (vc << 3);
  const short* ksrc = kvb + (size_t)((b << 10) + l16) * 512 + (h << 5) + (quad << 3);
  const float2* psrc = (const float2*)pos + (((b << 1) + g) << 10) + t;

  f32x4 Oacc[2] = {};
  f32x4 lacc = {};

  // ---- prefetch kt=0's V row + pos into registers
  bf16x8 vv_cur = *(const bf16x8*)vsrc;
  vsrc += 32768;
  float2 pp_cur = make_float2(0.f, 0.f);
  if (t < 64) pp_cur = *psrc;
  psrc += 64;

  for (int kt = 0; kt < 16; kt++) {
    __syncthreads();  // [b1] prior PV reads done (covers rpe8 copy at kt=0)
    // ---- stage V^T from the prefetched registers (pure ds_write now)
#pragma unroll
    for (int k2 = 0; k2 < 8; k2++) Vt[((vc << 3) + k2) * 68 + vj] = vv_cur[k2];
    if (t < 64)
      posT[t] = make_float2(-15.5f * pp_cur.x, -15.5f * pp_cur.y);
    __syncthreads();  // [b2]

    // ---- issue NEXT kt's V/pos loads (complete under this kt's compute)
    bf16x8 vv_nxt = vv_cur;
    float2 pp_nxt = pp_cur;
    if (kt < 15) {
      vv_nxt = *(const bf16x8*)vsrc;
      if (t < 64) pp_nxt = *psrc;
    }
    vsrc += 32768; psrc += 64;

    // ---- QK^T first: 4 K B-frags from global (L1) + 4 MFMA, before bias
    f32x4 S[4];
#pragma unroll
    for (int jt = 0; jt < 4; jt++) {
      bf16x8 bk = *(const bf16x8*)(ksrc + (size_t)jt * 8192);
      f32x4 z = {};
      S[jt] = __builtin_amdgcn_mfma_f32_16x16x32_bf16(aq, bk, z, 0, 0, 0);
    }

    // ---- y-chains for the 4 j's (posT broadcast reads), hoisted (v12 exact)
    float fyv[4];
    int ybv[4];
    float wyv[4];
#pragma unroll
    for (int jt = 0; jt < 4; jt++) {
      float2 bv = posT[(jt << 4) + l16];
      float ys = ayc + bv.x;
      float y0f = floorf(ys);
      fyv[jt] = ys - y0f;
      ybv[jt] = (int)y0f << 6;
      wyv[jt] = bv.y;
    }

    // ---- bias sample + p = exp2(S+bias), per jt (v12 exact fmaf lerp)
    unsigned pu[4][2];
#pragma unroll
    for (int jt = 0; jt < 4; jt++) {
      float fy = fyv[jt];
      int ybase = ybv[jt];
      float pv[4];
#pragma unroll
      for (int r = 0; r < 4; r++) {
        float sx = ax[r] + wyv[jt];
        float x0f = floorf(sx);
        float fx = sx - x0f;
        unsigned u = rpe8[ybase + (int)x0f];
        float g00, g10, g01, g11;
        unpack_fp8_quad(u, g00, g10, g01, g11);
        float h0 = fmaf(fx, g01 - g00, g00);
        float h1 = fmaf(fx, g11 - g10, g10);
        float bias = fmaf(fy, h1 - h0, h0);
        pv[r] = exp2_fast(S[jt][r] + bias);
      }
      pu[jt][0] = pk2bf(pv[0], pv[1]);
      pu[jt][1] = pk2bf(pv[2], pv[3]);
    }

    // ---- wave-local P write -> A-frag read -> PV + l (no barrier)
#pragma unroll
    for (int jt = 0; jt < 4; jt++) {
      int cb = (jt << 4) + l16;
      int rb = ((wv << 4) + (quad << 2)) * 72 + cb;
      PL[rb]       = (short)(pu[jt][0] & 0xffff);
      PL[rb + 72]  = (short)(pu[jt][0] >> 16);
      PL[rb + 144] = (short)(pu[jt][1] & 0xffff);
      PL[rb + 216] = (short)(pu[jt][1] >> 16);
    }
    bf16x8 pa0 = *(const bf16x8*)&PL[((wv << 4) + l16) * 72 + (quad << 3)];
    bf16x8 pa1 = *(const bf16x8*)&PL[((wv << 4) + l16) * 72 + 32 + (quad << 3)];
#pragma unroll
    for (int dt = 0; dt < 2; dt++) {
      bf16x8 vb0 = *(const bf16x8*)&Vt[((dt << 4) + l16) * 68 + (quad << 3)];
      bf16x8 vb1 = *(const bf16x8*)&Vt[((dt << 4) + l16) * 68 + 32 + (quad << 3)];
      Oacc[dt] = __builtin_amdgcn_mfma_f32_16x16x32_bf16(pa0, vb0, Oacc[dt], 0, 0, 0);
      Oacc[dt] = __builtin_amdgcn_mfma_f32_16x16x32_bf16(pa1, vb1, Oacc[dt], 0, 0, 0);
    }
    lacc = __builtin_amdgcn_mfma_f32_16x16x32_bf16(pa0, vones, lacc, 0, 0, 0);
    lacc = __builtin_amdgcn_mfma_f32_16x16x32_bf16(pa1, vones, lacc, 0, 0, 0);

    // ---- pin the prefetch (issued above; latency hid under this compute)
    if (kt < 15) {
      uint4 p4 = __builtin_bit_cast(uint4, vv_nxt);
      asm volatile("" :: "v"(p4.x), "v"(p4.y), "v"(p4.z), "v"(p4.w),
                         "v"(pp_nxt.x), "v"(pp_nxt.y));
    }
    vv_cur = vv_nxt;
    pp_cur = pp_nxt;
    ksrc += 32768;   // THE FIX: advance K base to the next 64-row tile
  }

  // ---- epilogue -> ao bf16
#pragma unroll
  for (int r = 0; r < 4; r++) {
    float inv = 1.f / lacc[r];
    int row = row0 + (quad << 2) + r;
#pragma unroll
    for (int dt = 0; dt < 2; dt++) {
      ao[(size_t)((b << 10) + row) * 256 + (h << 5) + (dt << 4) + l16] =
          f2bf(Oacc[dt][r] * inv);
    }
  }
}

// ---------------------------------------------------------------------------
extern "C" void kernel_launch(void* const* d_in, const int* in_sizes, int n_in,
                              void* d_out, int out_size, void* d_ws, size_t ws_size,
                              hipStream_t stream) {
  (void)in_sizes; (void)n_in; (void)out_size; (void)ws_size;
  const float* x      = (const float*)d_in[0];
  const float* Wq     = (const float*)d_in[1];
  const float* Wkv    = (const float*)d_in[2];
  const float* conv_w = (const float*)d_in[3];
  const float* conv_b = (const float*)d_in[4];
  const float* ln_g   = (const float*)d_in[5];
  const float* ln_b   = (const float*)d_in[6];
  const float* Woff   = (const float*)d_in[7];
  const float* rpe    = (const float*)d_in[8];
  const float* Wout   = (const float*)d_in[9];
  const float* bout   = (const float*)d_in[10];
  float* out = (float*)d_out;

  float* ws      = (float*)d_ws;
  float* q       = ws;                        // [0 .. 2097152)
  float* pos     = ws + 2097152;              // [.. 2129920)
  short* kvb     = (short*)(ws + 2129920);    // 8192*512 bf16 = 2,097,152 f32 [.. 4227072)
  short* xsb     = (short*)(ws + 4227072);    // 8192*256 bf16 = 1,048,576 f32 [.. 5275648)
  short* aob     = (short*)(ws + 5275648);    // 8192*256 bf16 = 1,048,576 f32 [.. 6324224)
  short* Wkvt    = (short*)(ws + 6324224);    // 512*256 bf16  =    65,536 f32 [.. 6389760)
  short* Woutt   = (short*)(ws + 6389760);    // 256*256 bf16  =    32,768 f32 [.. 6422528)
  short* Wqt     = (short*)(ws + 6422528);    // 256*256 bf16  =    32,768 f32 [.. 6455296)
  unsigned* rpeq = (unsigned*)(ws + 6455296); // 8*4096 u32    =    32,768 f32 [.. 6488064)
  // total 6,488,064 f32 = 26.0 MB

  // 0. weight transposes + global fp8 rpe quad table (merged)
  prep_all<<<1152, 256, 0, stream>>>(Wkv, Wout, Wq, rpe, Wkvt, Woutt, Wqt, rpeq);
  // 1. q = x @ Wq (bf16 MFMA, f32 A staged+converted, f32 out)
  gemm_bf16<<<dim3(4, 128), 256, 0, stream>>>(nullptr, x, Wqt, q, nullptr, nullptr, 256);
  // 2+3. conv + LN + GELU + Woff + tanh -> pos, fused grid_sample -> xs
  conv_pos_sample_kernel<<<4096, 256, 0, stream>>>(q, conv_w, conv_b, ln_g, ln_b,
                                                   Woff, pos, xsb);
  // 4. kv = xs @ Wkv (bf16 MFMA, bf16 out)
  gemm_bf16<<<dim3(8, 128), 256, 0, stream>>>(xsb, nullptr, Wkvt, nullptr, kvb, nullptr, 512);
  // 5. fused attention v13c (pinned V/pos prefetch, fixed ksrc advance) -> ao
  attn_kernel<<<dim3(16, 8, 8), 256, 0, stream>>>(q, kvb, pos, rpeq, aob);
  // 6. out = ao @ Wout + bout (bf16 MFMA, f32 out)
  gemm_bf16<<<dim3(4, 128), 256, 0, stream>>>(aob, nullptr, Woutt, out, nullptr, bout, 256);
}